// Round 4
// baseline (12.496 us; speedup 1.0000x reference)
//
#include <hip/hip_runtime.h>

#define NB 4096
#define TPB 1024
#define WPB (TPB / 64)        // 16 waves (bodies) per block
#define NBLK (NB / WPB)       // 256 blocks -> 1 per CU
#define NPAIR (NB / 2)        // 2048 packed source-pairs
#define NT (NPAIR / 64)       // 32 iterations per lane (2 sources each)

// One wave per body k. Lane l handles source-pairs p = 64t + l (sources 2p, 2p+1).
// Sources packed in LDS as (qx0,qy0,qx1,qy1) float4 + (m0,m1) float2:
// 1 ds_read_b128 + 1 ds_read_b64 per TWO pairs. Single v_rsq_f32 per pair.
__global__ __launch_bounds__(TPB) void nbody_wave(
    const float* __restrict__ x, const float* __restrict__ m,
    float4* __restrict__ out)
{
    __shared__ float4 qp[NPAIR];  // 32 KB
    __shared__ float2 mp[NPAIR];  // 16 KB

    const int tid = threadIdx.x;

    #pragma unroll
    for (int t = 0; t < NPAIR / TPB; ++t) {   // 2 iters
        const int j = t * TPB + tid;
        const float4 a = ((const float4*)x)[2 * j];
        const float4 b = ((const float4*)x)[2 * j + 1];
        qp[j] = make_float4(a.x, a.y, b.x, b.y);
        mp[j] = ((const float2*)m)[j];
    }
    __syncthreads();

    const int wave = tid >> 6;
    const int lane = tid & 63;
    const int k = blockIdx.x * WPB + wave;

    const float4 xk = ((const float4*)x)[k];  // wave-uniform -> scalar load
    const float qx = xk.x, qy = xk.y;
    float ax = 0.f, ay = 0.f;

    // Self-pair (i==k): dx=dy=0, sq clamps to 1e-12 -> w finite, dx*w == 0.
    #pragma unroll 8
    for (int t = 0; t < NT; ++t) {
        const int p = t * 64 + lane;
        const float4 q = qp[p];
        const float2 mm = mp[p];
        {
            const float dx = qx - q.x;
            const float dy = qy - q.y;
            float sq = fmaf(dx, dx, dy * dy);
            sq = fmaxf(sq, 1e-12f);
            const float r = __builtin_amdgcn_rsqf(sq);
            const float w = r * r * r * mm.x;
            ax = fmaf(dx, w, ax);
            ay = fmaf(dy, w, ay);
        }
        {
            const float dx = qx - q.z;
            const float dy = qy - q.w;
            float sq = fmaf(dx, dx, dy * dy);
            sq = fmaxf(sq, 1e-12f);
            const float r = __builtin_amdgcn_rsqf(sq);
            const float w = r * r * r * mm.y;
            ax = fmaf(dx, w, ax);
            ay = fmaf(dy, w, ay);
        }
    }

    // Adjacent pairs |k-i|==1 carry weight 2 under tril(.,diagonal=1); main loop
    // counted them once. Lanes 0/1 add the extra unit weight.
    int nbi = -1;
    if (lane == 0 && k > 0) nbi = k - 1;
    else if (lane == 1 && k < NB - 1) nbi = k + 1;
    if (nbi >= 0) {
        const float4 q = qp[nbi >> 1];
        const float2 mm = mp[nbi >> 1];
        const float sx = (nbi & 1) ? q.z : q.x;
        const float sy = (nbi & 1) ? q.w : q.y;
        const float sm = (nbi & 1) ? mm.y : mm.x;
        const float dx = qx - sx;
        const float dy = qy - sy;
        const float sq = fmaf(dx, dx, dy * dy);
        const float r = __builtin_amdgcn_rsqf(sq);
        const float w = r * r * r * sm;
        ax = fmaf(dx, w, ax);
        ay = fmaf(dy, w, ay);
    }

    // Wave butterfly reduction (fixed order -> bitwise deterministic).
    #pragma unroll
    for (int off = 32; off > 0; off >>= 1) {
        ax += __shfl_xor(ax, off);
        ay += __shfl_xor(ay, off);
    }

    if (lane == 0) {
        const float m0inv = 1.0f / m[0];
        out[k] = make_float4(xk.z * m0inv, xk.w * m0inv, ax * m[k], ay * m[k]);
    }
}

extern "C" void kernel_launch(void* const* d_in, const int* in_sizes, int n_in,
                              void* d_out, int out_size, void* d_ws, size_t ws_size,
                              hipStream_t stream) {
    const float* x = (const float*)d_in[0];
    const float* m = (const float*)d_in[1];
    nbody_wave<<<dim3(NBLK), dim3(TPB), 0, stream>>>(x, m, (float4*)d_out);
}